// Round 1
// baseline (3262.991 us; speedup 1.0000x reference)
//
#include <hip/hip_runtime.h>

#define NN     100000
#define NP     100096   // padded to multiple of 128
#define HD     128
#define NE     400000
#define TOT    2400000  // 6 * NE
#define NLAYER 8
#define SCHUNK 2048

typedef unsigned short ushort_t;
typedef unsigned int   uint_t;

typedef __bf16 bf16x8 __attribute__((ext_vector_type(8)));
typedef float  f32x4  __attribute__((ext_vector_type(4)));

__device__ __forceinline__ f32x4 mfma16(bf16x8 a, bf16x8 b, f32x4 c) {
  return __builtin_amdgcn_mfma_f32_16x16x32_bf16(a, b, c, 0, 0, 0);
}

__device__ __forceinline__ unsigned short f2bf(float f) {
  unsigned int u = __builtin_bit_cast(unsigned int, f);
  u = (u + 0x7FFFu + ((u >> 16) & 1u)) >> 16;
  return (unsigned short)u;
}
__device__ __forceinline__ float bflo(uint_t v) { return __builtin_bit_cast(float, v << 16); }
__device__ __forceinline__ float bfhi(uint_t v) { return __builtin_bit_cast(float, v & 0xFFFF0000u); }
__device__ __forceinline__ uint_t packbf(float x, float y) {
  return (uint_t)f2bf(x) | ((uint_t)f2bf(y) << 16);
}

#define GLOAD_LDS16(g, l) __builtin_amdgcn_global_load_lds( \
    (__attribute__((address_space(1))) void*)(g),           \
    (__attribute__((address_space(3))) void*)(l), 16, 0, 0)

// ---------- setup kernels (once per call) ----------

__global__ __launch_bounds__(256) void k_init(const float* __restrict__ ns,
    float* __restrict__ oh, float* __restrict__ oold, ushort_t* __restrict__ hbf) {
  int i = blockIdx.x * 256 + threadIdx.x;
  if (i < NN * HD) {
    float v = ns[i];
    oh[i] = v; oold[i] = v; hbf[i] = f2bf(v);
  }
}

__global__ __launch_bounds__(256) void k_prep(const float* __restrict__ Wm,
    const float* __restrict__ wih, const float* __restrict__ whh,
    ushort_t* __restrict__ Wcat, ushort_t* __restrict__ wihb, ushort_t* __restrict__ whhb) {
  int t = blockIdx.x * 256 + threadIdx.x;
  if (t < 128 * 768) {
    int n = t / 768, k = t % 768;
    int e = k >> 7, d = k & 127;
    // Wcat_t[n][k] = W_msg[e][d][n]  (B stored N-major so frags are K-contiguous)
    Wcat[t] = f2bf(Wm[(e * 128 + d) * 128 + n]);
  }
  if (t < 384 * 128) {
    wihb[t] = f2bf(wih[t]);
    whhb[t] = f2bf(whh[t]);
  }
}

__global__ __launch_bounds__(256) void k_hist(const int* __restrict__ edges, int* __restrict__ cnt6) {
  int t = blockIdx.x * 256 + threadIdx.x;
  if (t >= TOT) return;
  int e = t / NE, m = t - e * NE;
  int tgt;
  if (e < 3) tgt = edges[(e * NE + m) * 2 + 1];
  else       tgt = edges[((e - 3) * NE + m) * 2];
  atomicAdd(&cnt6[tgt * 6 + e], 1);
}

__global__ __launch_bounds__(256) void k_div(const int* __restrict__ cnt6,
    float* __restrict__ divf, int* __restrict__ ctot) {
  int i = blockIdx.x * 256 + threadIdx.x;
  if (i < NN) {
    int c = 0;
#pragma unroll
    for (int e = 0; e < 6; e++) c += cnt6[i * 6 + e];
    ctot[i] = c;
    divf[i] = c ? (float)c : 1.0f;
  }
}

__global__ __launch_bounds__(256) void k_scan1(const int* __restrict__ ctot, int* __restrict__ bsum) {
  int base = blockIdx.x * SCHUNK + threadIdx.x * 8;
  int s = 0;
#pragma unroll
  for (int j = 0; j < 8; j++) { int idx = base + j; s += (idx < NN) ? ctot[idx] : 0; }
  for (int o = 32; o > 0; o >>= 1) s += __shfl_down(s, o);
  __shared__ int sm[4];
  if ((threadIdx.x & 63) == 0) sm[threadIdx.x >> 6] = s;
  __syncthreads();
  if (threadIdx.x == 0) bsum[blockIdx.x] = sm[0] + sm[1] + sm[2] + sm[3];
}

__global__ void k_scan2(int* bsum, int nb) {   // single block, 64 threads, nb <= 64
  int lane = threadIdx.x;
  int orig = (lane < nb) ? bsum[lane] : 0;
  int v = orig;
  for (int o = 1; o < 64; o <<= 1) { int t = __shfl_up(v, o); if (lane >= o) v += t; }
  if (lane < nb) bsum[lane] = v - orig;   // exclusive
}

__global__ __launch_bounds__(256) void k_scan3(const int* __restrict__ ctot,
    const int* __restrict__ bsum, int* __restrict__ offs) {
  int base = blockIdx.x * SCHUNK + threadIdx.x * 8;
  int vals[8], pre[8];
  int s = 0;
#pragma unroll
  for (int j = 0; j < 8; j++) {
    int idx = base + j;
    vals[j] = (idx < NN) ? ctot[idx] : 0;
    pre[j] = s; s += vals[j];
  }
  int lane = threadIdx.x & 63, wvi = threadIdx.x >> 6;
  int v = s;
  for (int o = 1; o < 64; o <<= 1) { int t = __shfl_up(v, o); if (lane >= o) v += t; }
  __shared__ int wsum[4];
  if (lane == 63) wsum[wvi] = v;
  __syncthreads();
  int wpre = 0;
  for (int w = 0; w < wvi; w++) wpre += wsum[w];
  int texcl = (v - s) + wpre + bsum[blockIdx.x];
#pragma unroll
  for (int j = 0; j < 8; j++) {
    int idx = base + j;
    if (idx < NN) {
      offs[idx] = texcl + pre[j];
      if (idx == NN - 1) offs[NN] = texcl + pre[j] + vals[j];
    }
  }
}

__global__ __launch_bounds__(256) void k_fill(const int* __restrict__ edges,
    int* __restrict__ cursor, int* __restrict__ entries) {
  int t = blockIdx.x * 256 + threadIdx.x;
  if (t >= TOT) return;
  int e = t / NE, m = t - e * NE;
  int src, tgt;
  if (e < 3) { int b = (e * NE + m) * 2;       src = edges[b];     tgt = edges[b + 1]; }
  else       { int b = ((e - 3) * NE + m) * 2; src = edges[b + 1]; tgt = edges[b]; }
  int pos = atomicAdd(&cursor[tgt], 1);
  entries[pos] = (e << 20) | src;  // src < 2^20, type in bits 20..22
}

// ---------- per-layer kernels ----------

// CSR gather-aggregation: one wave per node; lane l owns dims 2l,2l+1;
// edge type is wave-uniform -> uniform switch into register accumulators.
#define ACCADD(ET, V) do { float _x = bflo(V), _y = bfhi(V);            \
  switch (ET) {                                                          \
    case 0: racc[0].x += _x; racc[0].y += _y; break;                     \
    case 1: racc[1].x += _x; racc[1].y += _y; break;                     \
    case 2: racc[2].x += _x; racc[2].y += _y; break;                     \
    case 3: racc[3].x += _x; racc[3].y += _y; break;                     \
    case 4: racc[4].x += _x; racc[4].y += _y; break;                     \
    default: racc[5].x += _x; racc[5].y += _y; break; } } while (0)

__global__ __launch_bounds__(256) void k_agg(const ushort_t* __restrict__ hbf,
    const int* __restrict__ offs, const int* __restrict__ entries,
    ushort_t* __restrict__ agg, int node0, int rows) {
  int lane = threadIdx.x & 63, wv = threadIdx.x >> 6;
  int row = blockIdx.x * 4 + wv;
  if (row >= rows) return;
  int n = node0 + row;
  float2 racc[6];
#pragma unroll
  for (int j = 0; j < 6; j++) racc[j] = make_float2(0.f, 0.f);
  if (n < NN) {
    int s = offs[n], e = offs[n + 1];
    for (int i = s; i < e; i += 4) {   // 4 gathers in flight for latency hiding
      int i1 = i + 1 < e ? i + 1 : e - 1;
      int i2 = i + 2 < e ? i + 2 : e - 1;
      int i3 = i + 3 < e ? i + 3 : e - 1;
      int e0 = entries[i], e1 = entries[i1], e2 = entries[i2], e3 = entries[i3];
      uint_t v0 = *(const uint_t*)(hbf + (size_t)(e0 & 0xFFFFF) * HD + lane * 2);
      uint_t v1 = *(const uint_t*)(hbf + (size_t)(e1 & 0xFFFFF) * HD + lane * 2);
      uint_t v2 = *(const uint_t*)(hbf + (size_t)(e2 & 0xFFFFF) * HD + lane * 2);
      uint_t v3 = *(const uint_t*)(hbf + (size_t)(e3 & 0xFFFFF) * HD + lane * 2);
      ACCADD(e0 >> 20, v0);
      if (i + 1 < e) ACCADD(e1 >> 20, v1);
      if (i + 2 < e) ACCADD(e2 >> 20, v2);
      if (i + 3 < e) ACCADD(e3 >> 20, v3);
    }
  }
  // agg row layout: k = type*128 + d; uint j covers d = 2*(j%? ) -> j*128+2l,2l+1
  uint_t* outp = (uint_t*)(agg + (size_t)row * 768);
#pragma unroll
  for (int j = 0; j < 6; j++) outp[j * 64 + lane] = packbf(racc[j].x, racc[j].y);
}

// msgs = (agg_cat @ Wcat + sum_e cnt_e*b_msg_e) / div + 1e-8 ; M-tile 128, N=128, K=768
__global__ __launch_bounds__(256) void k_gemm1(const ushort_t* __restrict__ agg,
    const ushort_t* __restrict__ Wcat, const int* __restrict__ cnt6,
    const float* __restrict__ divf, const float* __restrict__ b_msg,
    ushort_t* __restrict__ msgs, int node0) {
  __shared__ ushort_t Alds[128 * 64];
  __shared__ ushort_t Blds[128 * 64];
  int lane = threadIdx.x & 63, wv = threadIdx.x >> 6;
  int wr = wv >> 1, wc = wv & 1;
  int rbase = blockIdx.x * 128;
  f32x4 acc[4][4] = {};
  for (int k0 = 0; k0 < 768; k0 += 64) {
#pragma unroll
    for (int i = 0; i < 4; i++) {
      int off = wv * 1024 + i * 4096;         // wave-uniform LDS base
      int loff = off + lane * 16;             // this lane's slot
      int r2 = loff >> 7, c16 = (loff >> 4) & 7;
      GLOAD_LDS16(agg + (size_t)(rbase + r2) * 768 + k0 + c16 * 8, (char*)Alds + off);
      GLOAD_LDS16(Wcat + (size_t)r2 * 768 + k0 + c16 * 8,          (char*)Blds + off);
    }
    __syncthreads();
#pragma unroll
    for (int kk = 0; kk < 2; kk++) {
      int kb = kk * 64 + ((lane >> 4) << 4);
      bf16x8 af[4], bfv[4];
#pragma unroll
      for (int m = 0; m < 4; m++) {
        af[m]  = *(const bf16x8*)((const char*)Alds + (wr * 64 + m * 16 + (lane & 15)) * 128 + kb);
        bfv[m] = *(const bf16x8*)((const char*)Blds + (wc * 64 + m * 16 + (lane & 15)) * 128 + kb);
      }
#pragma unroll
      for (int m = 0; m < 4; m++)
#pragma unroll
        for (int nf = 0; nf < 4; nf++)
          acc[m][nf] = mfma16(af[m], bfv[nf], acc[m][nf]);
    }
    __syncthreads();
  }
#pragma unroll
  for (int m = 0; m < 4; m++) {
#pragma unroll
    for (int r = 0; r < 4; r++) {
      int node = node0 + rbase + wr * 64 + m * 16 + (lane >> 4) * 4 + r;
      if (node < NN) {
        float dv = divf[node];
        const int* c6 = cnt6 + (size_t)node * 6;
#pragma unroll
        for (int nf = 0; nf < 4; nf++) {
          int col = wc * 64 + nf * 16 + (lane & 15);
          float badd = 0.f;
#pragma unroll
          for (int e = 0; e < 6; e++) badd += (float)c6[e] * b_msg[e * 128 + col];
          float v = (acc[m][nf][r] + badd) / dv + 1e-8f;
          msgs[(size_t)node * HD + col] = f2bf(v);
        }
      }
    }
  }
}

// Fused GRU: per block 64 nodes; 8 waves each own 16 output dims with all 6 gate
// columns (ir,iz,in from w_ih x msgs; hr,hz,hn from w_hh x h). Gates in-register.
__global__ __launch_bounds__(512) void k_gru(const ushort_t* __restrict__ msgs,
    const ushort_t* __restrict__ hbf, const ushort_t* __restrict__ wihb,
    const ushort_t* __restrict__ whhb, const float* __restrict__ b_ih,
    const float* __restrict__ b_hh, float* __restrict__ hf,
    ushort_t* __restrict__ hbfo) {
  __shared__ ushort_t Am[64 * 128];
  __shared__ ushort_t Ah[64 * 128];
  int lane = threadIdx.x & 63, wv = threadIdx.x >> 6;
  int rbase = blockIdx.x * 64;
#pragma unroll
  for (int i = 0; i < 2; i++) {
    int off = wv * 1024 + i * 8192;
    int loff = off + lane * 16;
    int r2 = loff >> 8, c16 = (loff >> 4) & 15;
    GLOAD_LDS16(msgs + (size_t)(rbase + r2) * HD + c16 * 8, (char*)Am + off);
    GLOAD_LDS16(hbf  + (size_t)(rbase + r2) * HD + c16 * 8, (char*)Ah + off);
  }
  __syncthreads();
  f32x4 acc[4][6] = {};
#pragma unroll
  for (int ks = 0; ks < 4; ks++) {
    int kb = ks * 64 + ((lane >> 4) << 4);
    bf16x8 am[4], ah[4];
#pragma unroll
    for (int m = 0; m < 4; m++) {
      int rb = (m * 16 + (lane & 15)) * 256 + kb;
      am[m] = *(const bf16x8*)((const char*)Am + rb);
      ah[m] = *(const bf16x8*)((const char*)Ah + rb);
    }
    bf16x8 bi[3], bh[3];
#pragma unroll
    for (int g = 0; g < 3; g++) {
      int n = g * 128 + wv * 16 + (lane & 15);
      int ko = ks * 32 + ((lane >> 4) << 3);
      bi[g] = *(const bf16x8*)(wihb + (size_t)n * HD + ko);
      bh[g] = *(const bf16x8*)(whhb + (size_t)n * HD + ko);
    }
#pragma unroll
    for (int m = 0; m < 4; m++) {
#pragma unroll
      for (int g = 0; g < 3; g++) {
        acc[m][g]     = mfma16(am[m], bi[g], acc[m][g]);
        acc[m][3 + g] = mfma16(ah[m], bh[g], acc[m][3 + g]);
      }
    }
  }
  int d = wv * 16 + (lane & 15);
  float bir = b_ih[d],       bhr = b_hh[d];
  float biz = b_ih[128 + d], bhz = b_hh[128 + d];
  float bin = b_ih[256 + d], bhn = b_hh[256 + d];
#pragma unroll
  for (int m = 0; m < 4; m++) {
#pragma unroll
    for (int r = 0; r < 4; r++) {
      int row = rbase + m * 16 + (lane >> 4) * 4 + r;
      if (row < NN) {
        float ir = acc[m][0][r], iz = acc[m][1][r], in = acc[m][2][r];
        float hr = acc[m][3][r], hz = acc[m][4][r], hn = acc[m][5][r];
        float rg = 1.f / (1.f + expf(-(ir + hr + bir + bhr)));
        float zg = 1.f / (1.f + expf(-(iz + hz + biz + bhz)));
        float ng = tanhf(in + bin + rg * (hn + bhn));
        size_t idx = (size_t)row * HD + d;
        float hold = hf[idx];
        float o = (1.f - zg) * ng + zg * hold;
        hf[idx] = o;
        hbfo[idx] = f2bf(o);
      }
    }
  }
}

// ---------- host ----------

extern "C" void kernel_launch(void* const* d_in, const int* in_sizes, int n_in,
                              void* d_out, int out_size, void* d_ws, size_t ws_size,
                              hipStream_t stream) {
  const float* node_states = (const float*)d_in[0];
  const int*   edges       = (const int*)d_in[1];
  const float* W_msg       = (const float*)d_in[2];
  const float* b_msg       = (const float*)d_in[3];
  const float* w_ih        = (const float*)d_in[4];
  const float* w_hh        = (const float*)d_in[5];
  const float* b_ih        = (const float*)d_in[6];
  const float* b_hh        = (const float*)d_in[7];
  float* out_h   = (float*)d_out;                 // h lives in d_out, updated in place
  float* out_old = out_h + (size_t)NN * HD;

  char* p = (char*)d_ws;
  auto carve = [&](size_t bytes) { char* r = p; p += (bytes + 255) & ~(size_t)255; return r; };
  ushort_t* hbf  = (ushort_t*)carve((size_t)NP * HD * 2);
  ushort_t* msgs = (ushort_t*)carve((size_t)NP * HD * 2);
  ushort_t* Wcat = (ushort_t*)carve((size_t)128 * 768 * 2);
  ushort_t* wihb = (ushort_t*)carve((size_t)384 * 128 * 2);
  ushort_t* whhb = (ushort_t*)carve((size_t)384 * 128 * 2);
  int*   cnt6    = (int*)carve((size_t)NN * 6 * 4);
  float* divf    = (float*)carve((size_t)NN * 4);
  int*   ctot    = (int*)carve((size_t)NN * 4);
  int*   offs    = (int*)carve((size_t)(NN + 1) * 4);
  int*   cursor  = (int*)carve((size_t)NN * 4);
  int*   entries = (int*)carve((size_t)TOT * 4);
  int*   bsum    = (int*)carve(64 * 4);
  size_t used  = (size_t)(p - (char*)d_ws);
  size_t avail = ws_size > used ? ws_size - used : 0;
  size_t chunk_rows = avail / (768 * 2);           // agg chunk sized to remaining ws
  if (chunk_rows > (size_t)NP) chunk_rows = NP;
  chunk_rows &= ~(size_t)127;
  if (chunk_rows < 128) chunk_rows = 128;
  ushort_t* agg = (ushort_t*)p;

  hipMemsetAsync(cnt6, 0, (size_t)NN * 6 * 4, stream);
  hipMemsetAsync(hbf  + (size_t)NN * HD, 0, (size_t)(NP - NN) * HD * 2, stream);
  hipMemsetAsync(msgs + (size_t)NN * HD, 0, (size_t)(NP - NN) * HD * 2, stream);

  k_init<<<(NN * HD + 255) / 256, 256, 0, stream>>>(node_states, out_h, out_old, hbf);
  k_prep<<<(128 * 768 + 255) / 256, 256, 0, stream>>>(W_msg, w_ih, w_hh, Wcat, wihb, whhb);
  k_hist<<<(TOT + 255) / 256, 256, 0, stream>>>(edges, cnt6);
  k_div<<<(NN + 255) / 256, 256, 0, stream>>>(cnt6, divf, ctot);
  int nb = (NN + SCHUNK - 1) / SCHUNK;
  k_scan1<<<nb, 256, 0, stream>>>(ctot, bsum);
  k_scan2<<<1, 64, 0, stream>>>(bsum, nb);
  k_scan3<<<nb, 256, 0, stream>>>(ctot, bsum, offs);
  hipMemcpyAsync(cursor, offs, (size_t)NN * 4, hipMemcpyDeviceToDevice, stream);
  k_fill<<<(TOT + 255) / 256, 256, 0, stream>>>(edges, cursor, entries);

  for (int L = 0; L < NLAYER; L++) {
    for (size_t n0 = 0; n0 < (size_t)NP; n0 += chunk_rows) {
      int rows = (int)(((size_t)NP - n0) < chunk_rows ? ((size_t)NP - n0) : chunk_rows);
      k_agg<<<rows / 4, 256, 0, stream>>>(hbf, offs, entries, agg, (int)n0, rows);
      k_gemm1<<<rows / 128, 256, 0, stream>>>(agg, Wcat, cnt6, divf, b_msg, msgs, (int)n0);
    }
    k_gru<<<NP / 64, 512, 0, stream>>>(msgs, hbf, wihb, whhb, b_ih, b_hh, out_h, hbf);
  }
}